// Round 1
// baseline (1445.176 us; speedup 1.0000x reference)
//
#include <hip/hip_runtime.h>

#define H1 15
#define H2 81
#define FXS 10
#define FXT 5
#define FE 10
#define FU 10
#define SCAN_B 1024

// ---------------- CSR build ----------------

__global__ void k_hist(const int* __restrict__ src, int* __restrict__ cnt, int E) {
    int e = blockIdx.x * blockDim.x + threadIdx.x;
    if (e < E) atomicAdd(&cnt[src[e]], 1);
}

// block-level exclusive scan (Hillis-Steele in LDS), emits block totals
__global__ void k_scan1(const int* __restrict__ cnt, int* __restrict__ offs,
                        int* __restrict__ bsum, int NSs) {
    __shared__ int lds[SCAN_B];
    int t = threadIdx.x, g = blockIdx.x * SCAN_B + t;
    int v = (g < NSs) ? cnt[g] : 0;
    lds[t] = v;
    __syncthreads();
    for (int d = 1; d < SCAN_B; d <<= 1) {
        int add = (t >= d) ? lds[t - d] : 0;
        __syncthreads();
        lds[t] += add;
        __syncthreads();
    }
    int incl = lds[t];
    if (g < NSs) offs[g] = incl - v;   // exclusive within block
    if (t == SCAN_B - 1) bsum[blockIdx.x] = incl;
}

// single-block exclusive scan of block totals (nb <= 1024)
__global__ void k_scan2(int* __restrict__ bsum, int nb) {
    __shared__ int lds[SCAN_B];
    int t = threadIdx.x;
    int v = (t < nb) ? bsum[t] : 0;
    lds[t] = v;
    __syncthreads();
    for (int d = 1; d < SCAN_B; d <<= 1) {
        int add = (t >= d) ? lds[t - d] : 0;
        __syncthreads();
        lds[t] += add;
        __syncthreads();
    }
    if (t < nb) bsum[t] = lds[t] - v;
}

__global__ void k_scan3(int* __restrict__ offs, const int* __restrict__ bsum, int NSs) {
    int g = blockIdx.x * SCAN_B + threadIdx.x;
    if (g < NSs) offs[g] += bsum[blockIdx.x];
}

__global__ void k_scatter(const int* __restrict__ src, const int* __restrict__ tgt,
                          const int* __restrict__ offs, int* __restrict__ cursor,
                          int2* __restrict__ csr, int E) {
    int e = blockIdx.x * blockDim.x + threadIdx.x;
    if (e >= E) return;
    int s = src[e];
    int pos = offs[s] + atomicAdd(&cursor[s], 1);
    csr[pos] = make_int2(tgt[e], e);
}

// ---------------- fused node kernel ----------------
// one thread per source node: walk CSR edges, edge MLP on the fly,
// raw moments in registers, then node MLP.

__global__ __launch_bounds__(256) void k_node(
    const float* __restrict__ x_s, const float* __restrict__ x_t,
    const float* __restrict__ ea, const float* __restrict__ u,
    const float* __restrict__ W1, const float* __restrict__ b1,
    const float* __restrict__ W2, const float* __restrict__ b2,
    const float* __restrict__ W3, const float* __restrict__ b3,
    const float* __restrict__ W4, const float* __restrict__ b4,
    const int* __restrict__ batch_s,
    const int* __restrict__ cnt, const int* __restrict__ offs,
    const int2* __restrict__ csr,
    float* __restrict__ out, int NSs) {
    __shared__ float sW1[H1 * H1], sb1[H1], sW2[H1 * H1], sb2[H1];
    __shared__ float sW3[H2 * FXS], sb3[FXS], sW4[FXS * FXS], sb4[FXS];
    for (int i = threadIdx.x; i < H1 * H1; i += blockDim.x) { sW1[i] = W1[i]; sW2[i] = W2[i]; }
    for (int i = threadIdx.x; i < H2 * FXS; i += blockDim.x) sW3[i] = W3[i];
    for (int i = threadIdx.x; i < FXS * FXS; i += blockDim.x) sW4[i] = W4[i];
    if (threadIdx.x < H1) { sb1[threadIdx.x] = b1[threadIdx.x]; sb2[threadIdx.x] = b2[threadIdx.x]; }
    if (threadIdx.x < FXS) { sb3[threadIdx.x] = b3[threadIdx.x]; sb4[threadIdx.x] = b4[threadIdx.x]; }
    __syncthreads();

    int s = blockIdx.x * blockDim.x + threadIdx.x;
    if (s >= NSs) return;
    int n = cnt[s], start = offs[s];

    float s1[H1], s2[H1], s3[H1], s4[H1];
#pragma unroll
    for (int j = 0; j < H1; j++) { s1[j] = 0.f; s2[j] = 0.f; s3[j] = 0.f; s4[j] = 0.f; }

    for (int k = 0; k < n; k++) {
        int2 te = csr[start + k];
        int tt = te.x;
        const float* ear = ea + (size_t)te.y * FE;
        float f[H1];
#pragma unroll
        for (int i = 0; i < FXT; i++) f[i] = x_t[(size_t)tt * FXT + i];
        // edge_attr rows are 40B, 8B-aligned -> float2 loads
        const float2* e2 = (const float2*)ear;
#pragma unroll
        for (int i = 0; i < FE / 2; i++) {
            float2 v = e2[i];
            f[FXT + 2 * i] = v.x;
            f[FXT + 2 * i + 1] = v.y;
        }
        float h[H1];
#pragma unroll
        for (int j = 0; j < H1; j++) {
            float acc = sb1[j];
#pragma unroll
            for (int i = 0; i < H1; i++) acc = fmaf(f[i], sW1[i * H1 + j], acc);
            h[j] = fmaxf(acc, 0.1f * acc);   // leaky relu
        }
#pragma unroll
        for (int j = 0; j < H1; j++) {
            float acc = sb2[j];
#pragma unroll
            for (int i = 0; i < H1; i++) acc = fmaf(h[i], sW2[i * H1 + j], acc);
            float x = acc, x2 = x * x;
            s1[j] += x;
            s2[j] = fmaf(x, x, s2[j]);
            s3[j] = fmaf(x2, x, s3[j]);
            s4[j] = fmaf(x2, x2, s4[j]);
        }
    }

    float inv = 1.0f / (float)(n > 1 ? n : 1);
    float feat[H2];
#pragma unroll
    for (int i = 0; i < FXS; i++) feat[i] = x_s[(size_t)s * FXS + i];
    feat[FXS] = (float)n;
#pragma unroll
    for (int j = 0; j < H1; j++) {
        float a = s1[j] * inv, m2 = s2[j] * inv, m3 = s3[j] * inv, m4 = s4[j] * inv;
        float a2 = a * a;
        float var = m2 - a2;
        float bb = sqrtf(1e-6f + fmaxf(var, 0.0f));
        float c3 = m3 - 3.0f * a * m2 + 2.0f * a * a2;
        float c4 = m4 - 4.0f * a * m3 + 6.0f * a2 * m2 - 3.0f * a2 * a2;
        float ib = 1.0f / bb, ib2 = ib * ib;
        feat[FXS + 1 + j] = a;
        feat[FXS + 1 + H1 + j] = bb;
        feat[FXS + 1 + 2 * H1 + j] = c3 * ib * ib2;
        feat[FXS + 1 + 3 * H1 + j] = c4 * ib2 * ib2;
    }
    int bidx = batch_s[s];
#pragma unroll
    for (int i = 0; i < FU; i++) feat[FXS + 1 + 4 * H1 + i] = u[(size_t)bidx * FU + i];

    float l1[FXS];
#pragma unroll
    for (int j = 0; j < FXS; j++) {
        float acc = sb3[j];
#pragma unroll
        for (int i = 0; i < H2; i++) acc = fmaf(feat[i], sW3[i * FXS + j], acc);
        l1[j] = fmaxf(acc, 0.1f * acc);
    }
#pragma unroll
    for (int j = 0; j < FXS; j++) {
        float acc = sb4[j];
#pragma unroll
        for (int i = 0; i < FXS; i++) acc = fmaf(l1[i], sW4[i * FXS + j], acc);
        out[(size_t)s * FXS + j] = acc;
    }
}

extern "C" void kernel_launch(void* const* d_in, const int* in_sizes, int n_in,
                              void* d_out, int out_size, void* d_ws, size_t ws_size,
                              hipStream_t stream) {
    const float* x_s = (const float*)d_in[0];
    const float* x_t = (const float*)d_in[1];
    const float* ea  = (const float*)d_in[2];
    const float* u   = (const float*)d_in[3];
    const float* W1  = (const float*)d_in[4];
    const float* b1  = (const float*)d_in[5];
    const float* W2  = (const float*)d_in[6];
    const float* b2  = (const float*)d_in[7];
    const float* W3  = (const float*)d_in[8];
    const float* b3  = (const float*)d_in[9];
    const float* W4  = (const float*)d_in[10];
    const float* b4  = (const float*)d_in[11];
    const int* src   = (const int*)d_in[12];
    const int* tgt   = (const int*)d_in[13];
    const int* batch_s = (const int*)d_in[14];

    int NSs = in_sizes[0] / FXS;
    int E   = in_sizes[2] / FE;

    // workspace layout (256B-aligned slices)
    char* w = (char*)d_ws;
    auto align_up = [](size_t x) { return (x + 255) & ~(size_t)255; };
    int* cnt = (int*)w;     w += align_up((size_t)NSs * 4);
    int* offs = (int*)w;    w += align_up((size_t)NSs * 4);
    int* cursor = (int*)w;  w += align_up((size_t)NSs * 4);
    int* bsum = (int*)w;    w += 64 * 1024;
    int2* csr = (int2*)w;   // E * 8 bytes

    hipMemsetAsync(cnt, 0, (size_t)NSs * 4, stream);
    hipMemsetAsync(cursor, 0, (size_t)NSs * 4, stream);

    k_hist<<<(E + 255) / 256, 256, 0, stream>>>(src, cnt, E);

    int nb = (NSs + SCAN_B - 1) / SCAN_B;
    k_scan1<<<nb, SCAN_B, 0, stream>>>(cnt, offs, bsum, NSs);
    k_scan2<<<1, SCAN_B, 0, stream>>>(bsum, nb);
    k_scan3<<<nb, SCAN_B, 0, stream>>>(offs, bsum, NSs);

    k_scatter<<<(E + 255) / 256, 256, 0, stream>>>(src, tgt, offs, cursor, csr, E);

    k_node<<<(NSs + 255) / 256, 256, 0, stream>>>(
        x_s, x_t, ea, u, W1, b1, W2, b2, W3, b3, W4, b4,
        batch_s, cnt, offs, csr, (float*)d_out, NSs);
}

// Round 2
// 481.355 us; speedup vs baseline: 3.0023x; 3.0023x over previous
//
#include <hip/hip_runtime.h>
#include <hip/hip_fp16.h>

#define H1 15
#define H2 81
#define FXS 10
#define FXT 5
#define FE 10
#define FU 10
#define SCAN_B 1024

// ---------------- CSR build ----------------

__global__ void k_hist(const int* __restrict__ src, int* __restrict__ cnt, int E) {
    int e = blockIdx.x * blockDim.x + threadIdx.x;
    if (e < E) atomicAdd(&cnt[src[e]], 1);
}

__global__ void k_scan1(const int* __restrict__ cnt, int* __restrict__ offs,
                        int* __restrict__ bsum, int NSs) {
    __shared__ int lds[SCAN_B];
    int t = threadIdx.x, g = blockIdx.x * SCAN_B + t;
    int v = (g < NSs) ? cnt[g] : 0;
    lds[t] = v;
    __syncthreads();
    for (int d = 1; d < SCAN_B; d <<= 1) {
        int add = (t >= d) ? lds[t - d] : 0;
        __syncthreads();
        lds[t] += add;
        __syncthreads();
    }
    int incl = lds[t];
    if (g < NSs) offs[g] = incl - v;
    if (t == SCAN_B - 1) bsum[blockIdx.x] = incl;
}

__global__ void k_scan2(int* __restrict__ bsum, int nb) {
    __shared__ int lds[SCAN_B];
    int t = threadIdx.x;
    int v = (t < nb) ? bsum[t] : 0;
    lds[t] = v;
    __syncthreads();
    for (int d = 1; d < SCAN_B; d <<= 1) {
        int add = (t >= d) ? lds[t - d] : 0;
        __syncthreads();
        lds[t] += add;
        __syncthreads();
    }
    if (t < nb) bsum[t] = lds[t] - v;
}

__global__ void k_scan3(int* __restrict__ offs, const int* __restrict__ bsum, int NSs) {
    int g = blockIdx.x * SCAN_B + threadIdx.x;
    if (g < NSs) offs[g] += bsum[blockIdx.x];
}

// write per-edge destination slot (CSR position); order within a node is arbitrary
__global__ void k_pos(const int* __restrict__ src, const int* __restrict__ offs,
                      int* __restrict__ cursor, int* __restrict__ epos, int E) {
    int e = blockIdx.x * blockDim.x + threadIdx.x;
    if (e >= E) return;
    int s = src[e];
    epos[e] = offs[s] + atomicAdd(&cursor[s], 1);
}

// old-path scatter (fallback only)
__global__ void k_scatter(const int* __restrict__ src, const int* __restrict__ tgt,
                          const int* __restrict__ offs, int* __restrict__ cursor,
                          int2* __restrict__ csr, int E) {
    int e = blockIdx.x * blockDim.x + threadIdx.x;
    if (e >= E) return;
    int s = src[e];
    int pos = offs[s] + atomicAdd(&cursor[s], 1);
    csr[pos] = make_int2(tgt[e], e);
}

// ---------------- edge MLP (edge-parallel, coalesced ea reads) ----------------
// weights read with wave-uniform indices -> scalar loads (K$), no LDS pressure

__global__ __launch_bounds__(256) void k_edge(
    const float* __restrict__ x_t, const float* __restrict__ ea,
    const float* __restrict__ W1, const float* __restrict__ b1,
    const float* __restrict__ W2, const float* __restrict__ b2,
    const int* __restrict__ tgt, const int* __restrict__ epos,
    __half* __restrict__ buf, int E)
{
    int e = blockIdx.x * blockDim.x + threadIdx.x;
    if (e >= E) return;
    int tt = tgt[e];
    int pos = epos[e];

    float f[H1];
#pragma unroll
    for (int i = 0; i < FXT; i++) f[i] = x_t[(size_t)tt * FXT + i];
    const float2* e2 = (const float2*)(ea + (size_t)e * FE);
#pragma unroll
    for (int i = 0; i < FE / 2; i++) {
        float2 v = e2[i];
        f[FXT + 2 * i] = v.x;
        f[FXT + 2 * i + 1] = v.y;
    }

    float h[H1];
#pragma unroll
    for (int j = 0; j < H1; j++) {
        float acc = b1[j];
#pragma unroll
        for (int i = 0; i < H1; i++) acc = fmaf(f[i], W1[i * H1 + j], acc);
        h[j] = fmaxf(acc, 0.1f * acc);
    }

    float o[H1];
#pragma unroll
    for (int j = 0; j < H1; j++) {
        float acc = b2[j];
#pragma unroll
        for (int i = 0; i < H1; i++) acc = fmaf(h[i], W2[i * H1 + j], acc);
        o[j] = acc;
    }

    // pack 15 fp16 + 1 pad into one 32B row (two uint4 stores)
    unsigned int w[8];
#pragma unroll
    for (int i = 0; i < 7; i++) {
        unsigned int lo = __half_as_ushort(__float2half(o[2 * i]));
        unsigned int hi = __half_as_ushort(__float2half(o[2 * i + 1]));
        w[i] = lo | (hi << 16);
    }
    w[7] = (unsigned int)__half_as_ushort(__float2half(o[14]));  // pad half = 0

    uint4* dst = (uint4*)(buf + (size_t)pos * 16);
    dst[0] = make_uint4(w[0], w[1], w[2], w[3]);
    dst[1] = make_uint4(w[4], w[5], w[6], w[7]);
}

// ---------------- moments + node MLP (16 lanes per node) ----------------

__global__ __launch_bounds__(256) void k_moments(
    const float* __restrict__ x_s, const float* __restrict__ u,
    const float* __restrict__ W3, const float* __restrict__ b3,
    const float* __restrict__ W4, const float* __restrict__ b4,
    const int* __restrict__ batch_s,
    const int* __restrict__ cnt, const int* __restrict__ offs,
    const __half* __restrict__ buf,
    float* __restrict__ out, int NSs)
{
    __shared__ float sW3[H2 * FXS], sb3[FXS], sW4[FXS * FXS], sb4[FXS];
    __shared__ float feat[16][H2 + 3];   // 84-float stride
    __shared__ float l1s[16][12];

    for (int i = threadIdx.x; i < H2 * FXS; i += blockDim.x) sW3[i] = W3[i];
    for (int i = threadIdx.x; i < FXS * FXS; i += blockDim.x) sW4[i] = W4[i];
    if (threadIdx.x < FXS) { sb3[threadIdx.x] = b3[threadIdx.x]; sb4[threadIdx.x] = b4[threadIdx.x]; }
    __syncthreads();

    int g = threadIdx.x >> 4;        // node group within block
    int j = threadIdx.x & 15;        // feature lane
    int s = blockIdx.x * 16 + g;
    bool valid = (s < NSs);

    int n = 0, start = 0;
    if (valid) { n = cnt[s]; start = offs[s]; }

    if (valid && j < H1) {
        float s1 = 0.f, s2 = 0.f, s3 = 0.f, s4 = 0.f;
        const __half* p = buf + (size_t)start * 16 + j;
        for (int k = 0; k < n; k++) {
            float x = __half2float(p[(size_t)k * 16]);
            float x2 = x * x;
            s1 += x;
            s2 = fmaf(x, x, s2);
            s3 = fmaf(x2, x, s3);
            s4 = fmaf(x2, x2, s4);
        }
        float inv = 1.0f / (float)(n > 1 ? n : 1);
        float a = s1 * inv, m2 = s2 * inv, m3 = s3 * inv, m4 = s4 * inv;
        float a2 = a * a;
        float var = m2 - a2;
        float bb = sqrtf(1e-6f + fmaxf(var, 0.0f));
        float c3 = m3 - 3.0f * a * m2 + 2.0f * a * a2;
        float c4 = m4 - 4.0f * a * m3 + 6.0f * a2 * m2 - 3.0f * a2 * a2;
        float ib = 1.0f / bb, ib2 = ib * ib;
        feat[g][FXS + 1 + j] = a;
        feat[g][FXS + 1 + H1 + j] = bb;
        feat[g][FXS + 1 + 2 * H1 + j] = c3 * ib * ib2;
        feat[g][FXS + 1 + 3 * H1 + j] = c4 * ib2 * ib2;
    }
    if (valid && j < FXS) {
        feat[g][j] = x_s[(size_t)s * FXS + j];
        feat[g][FXS + 1 + 4 * H1 + j] = u[(size_t)batch_s[s] * FU + j];
    }
    if (valid && j == 15) feat[g][FXS] = (float)n;
    __syncthreads();

    if (valid && j < FXS) {
        float acc = sb3[j];
#pragma unroll
        for (int i = 0; i < H2; i++) acc = fmaf(feat[g][i], sW3[i * FXS + j], acc);
        l1s[g][j] = fmaxf(acc, 0.1f * acc);
    }
    __syncthreads();

    if (valid && j < FXS) {
        float acc = sb4[j];
#pragma unroll
        for (int i = 0; i < FXS; i++) acc = fmaf(l1s[g][i], sW4[i * FXS + j], acc);
        out[(size_t)s * FXS + j] = acc;
    }
}

// ---------------- fallback: round-1 fused node kernel ----------------

__global__ __launch_bounds__(256) void k_node(
    const float* __restrict__ x_s, const float* __restrict__ x_t,
    const float* __restrict__ ea, const float* __restrict__ u,
    const float* __restrict__ W1, const float* __restrict__ b1,
    const float* __restrict__ W2, const float* __restrict__ b2,
    const float* __restrict__ W3, const float* __restrict__ b3,
    const float* __restrict__ W4, const float* __restrict__ b4,
    const int* __restrict__ batch_s,
    const int* __restrict__ cnt, const int* __restrict__ offs,
    const int2* __restrict__ csr,
    float* __restrict__ out, int NSs) {
    __shared__ float sW1[H1 * H1], sb1[H1], sW2[H1 * H1], sb2[H1];
    __shared__ float sW3[H2 * FXS], sb3[FXS], sW4[FXS * FXS], sb4[FXS];
    for (int i = threadIdx.x; i < H1 * H1; i += blockDim.x) { sW1[i] = W1[i]; sW2[i] = W2[i]; }
    for (int i = threadIdx.x; i < H2 * FXS; i += blockDim.x) sW3[i] = W3[i];
    for (int i = threadIdx.x; i < FXS * FXS; i += blockDim.x) sW4[i] = W4[i];
    if (threadIdx.x < H1) { sb1[threadIdx.x] = b1[threadIdx.x]; sb2[threadIdx.x] = b2[threadIdx.x]; }
    if (threadIdx.x < FXS) { sb3[threadIdx.x] = b3[threadIdx.x]; sb4[threadIdx.x] = b4[threadIdx.x]; }
    __syncthreads();

    int s = blockIdx.x * blockDim.x + threadIdx.x;
    if (s >= NSs) return;
    int n = cnt[s], start = offs[s];

    float s1[H1], s2[H1], s3[H1], s4[H1];
#pragma unroll
    for (int j = 0; j < H1; j++) { s1[j] = 0.f; s2[j] = 0.f; s3[j] = 0.f; s4[j] = 0.f; }

    for (int k = 0; k < n; k++) {
        int2 te = csr[start + k];
        int tt = te.x;
        const float* ear = ea + (size_t)te.y * FE;
        float f[H1];
#pragma unroll
        for (int i = 0; i < FXT; i++) f[i] = x_t[(size_t)tt * FXT + i];
        const float2* e2 = (const float2*)ear;
#pragma unroll
        for (int i = 0; i < FE / 2; i++) {
            float2 v = e2[i];
            f[FXT + 2 * i] = v.x;
            f[FXT + 2 * i + 1] = v.y;
        }
        float h[H1];
#pragma unroll
        for (int j = 0; j < H1; j++) {
            float acc = sb1[j];
#pragma unroll
            for (int i = 0; i < H1; i++) acc = fmaf(f[i], sW1[i * H1 + j], acc);
            h[j] = fmaxf(acc, 0.1f * acc);
        }
#pragma unroll
        for (int j = 0; j < H1; j++) {
            float acc = sb2[j];
#pragma unroll
            for (int i = 0; i < H1; i++) acc = fmaf(h[i], sW2[i * H1 + j], acc);
            float x = acc, x2 = x * x;
            s1[j] += x;
            s2[j] = fmaf(x, x, s2[j]);
            s3[j] = fmaf(x2, x, s3[j]);
            s4[j] = fmaf(x2, x2, s4[j]);
        }
    }

    float inv = 1.0f / (float)(n > 1 ? n : 1);
    float feat[H2];
#pragma unroll
    for (int i = 0; i < FXS; i++) feat[i] = x_s[(size_t)s * FXS + i];
    feat[FXS] = (float)n;
#pragma unroll
    for (int j = 0; j < H1; j++) {
        float a = s1[j] * inv, m2 = s2[j] * inv, m3 = s3[j] * inv, m4 = s4[j] * inv;
        float a2 = a * a;
        float var = m2 - a2;
        float bb = sqrtf(1e-6f + fmaxf(var, 0.0f));
        float c3 = m3 - 3.0f * a * m2 + 2.0f * a * a2;
        float c4 = m4 - 4.0f * a * m3 + 6.0f * a2 * m2 - 3.0f * a2 * a2;
        float ib = 1.0f / bb, ib2 = ib * ib;
        feat[FXS + 1 + j] = a;
        feat[FXS + 1 + H1 + j] = bb;
        feat[FXS + 1 + 2 * H1 + j] = c3 * ib * ib2;
        feat[FXS + 1 + 3 * H1 + j] = c4 * ib2 * ib2;
    }
    int bidx = batch_s[s];
#pragma unroll
    for (int i = 0; i < FU; i++) feat[FXS + 1 + 4 * H1 + i] = u[(size_t)bidx * FU + i];

    float l1[FXS];
#pragma unroll
    for (int j = 0; j < FXS; j++) {
        float acc = sb3[j];
#pragma unroll
        for (int i = 0; i < H2; i++) acc = fmaf(feat[i], sW3[i * FXS + j], acc);
        l1[j] = fmaxf(acc, 0.1f * acc);
    }
#pragma unroll
    for (int j = 0; j < FXS; j++) {
        float acc = sb4[j];
#pragma unroll
        for (int i = 0; i < FXS; i++) acc = fmaf(l1[i], sW4[i * FXS + j], acc);
        out[(size_t)s * FXS + j] = acc;
    }
}

extern "C" void kernel_launch(void* const* d_in, const int* in_sizes, int n_in,
                              void* d_out, int out_size, void* d_ws, size_t ws_size,
                              hipStream_t stream) {
    const float* x_s = (const float*)d_in[0];
    const float* x_t = (const float*)d_in[1];
    const float* ea  = (const float*)d_in[2];
    const float* u   = (const float*)d_in[3];
    const float* W1  = (const float*)d_in[4];
    const float* b1  = (const float*)d_in[5];
    const float* W2  = (const float*)d_in[6];
    const float* b2  = (const float*)d_in[7];
    const float* W3  = (const float*)d_in[8];
    const float* b3  = (const float*)d_in[9];
    const float* W4  = (const float*)d_in[10];
    const float* b4  = (const float*)d_in[11];
    const int* src   = (const int*)d_in[12];
    const int* tgt   = (const int*)d_in[13];
    const int* batch_s = (const int*)d_in[14];

    int NSs = in_sizes[0] / FXS;
    int E   = in_sizes[2] / FE;

    auto align_up = [](size_t x) { return (x + 255) & ~(size_t)255; };
    char* w = (char*)d_ws;
    int* cnt = (int*)w;     w += align_up((size_t)NSs * 4);
    int* offs = (int*)w;    w += align_up((size_t)NSs * 4);
    int* cursor = (int*)w;  w += align_up((size_t)NSs * 4);
    int* bsum = (int*)w;    w += 64 * 1024;
    char* tail = w;
    size_t head = (size_t)(tail - (char*)d_ws);
    size_t need_fast = head + align_up((size_t)E * 4) + (size_t)E * 32;

    hipMemsetAsync(cnt, 0, (size_t)NSs * 4, stream);
    hipMemsetAsync(cursor, 0, (size_t)NSs * 4, stream);

    k_hist<<<(E + 255) / 256, 256, 0, stream>>>(src, cnt, E);
    int nb = (NSs + SCAN_B - 1) / SCAN_B;
    k_scan1<<<nb, SCAN_B, 0, stream>>>(cnt, offs, bsum, NSs);
    k_scan2<<<1, SCAN_B, 0, stream>>>(bsum, nb);
    k_scan3<<<nb, SCAN_B, 0, stream>>>(offs, bsum, NSs);

    if (ws_size >= need_fast) {
        int* epos = (int*)tail;
        __half* buf = (__half*)(tail + align_up((size_t)E * 4));

        k_pos<<<(E + 255) / 256, 256, 0, stream>>>(src, offs, cursor, epos, E);
        k_edge<<<(E + 255) / 256, 256, 0, stream>>>(
            x_t, ea, W1, b1, W2, b2, tgt, epos, buf, E);
        k_moments<<<(NSs + 15) / 16, 256, 0, stream>>>(
            x_s, u, W3, b3, W4, b4, batch_s, cnt, offs, buf, (float*)d_out, NSs);
    } else {
        int2* csr = (int2*)tail;
        k_scatter<<<(E + 255) / 256, 256, 0, stream>>>(src, tgt, offs, cursor, csr, E);
        k_node<<<(NSs + 255) / 256, 256, 0, stream>>>(
            x_s, x_t, ea, u, W1, b1, W2, b2, W3, b3, W4, b4,
            batch_s, cnt, offs, csr, (float*)d_out, NSs);
    }
}

// Round 3
// 419.362 us; speedup vs baseline: 3.4461x; 1.1478x over previous
//
#include <hip/hip_runtime.h>
#include <hip/hip_fp16.h>

#define H1 15
#define H2 81
#define FXS 10
#define FXT 5
#define FE 10
#define FU 10
#define SCAN_B 1024

// ---------------- CSR build ----------------

__global__ void k_hist(const int* __restrict__ src, int* __restrict__ cnt, int E) {
    int e = blockIdx.x * blockDim.x + threadIdx.x;
    if (e < E) atomicAdd(&cnt[src[e]], 1);
}

__global__ void k_scan1(const int* __restrict__ cnt, int* __restrict__ offs,
                        int* __restrict__ bsum, int NSs) {
    __shared__ int lds[SCAN_B];
    int t = threadIdx.x, g = blockIdx.x * SCAN_B + t;
    int v = (g < NSs) ? cnt[g] : 0;
    lds[t] = v;
    __syncthreads();
    for (int d = 1; d < SCAN_B; d <<= 1) {
        int add = (t >= d) ? lds[t - d] : 0;
        __syncthreads();
        lds[t] += add;
        __syncthreads();
    }
    int incl = lds[t];
    if (g < NSs) offs[g] = incl - v;
    if (t == SCAN_B - 1) bsum[blockIdx.x] = incl;
}

__global__ void k_scan2(int* __restrict__ bsum, int nb) {
    __shared__ int lds[SCAN_B];
    int t = threadIdx.x;
    int v = (t < nb) ? bsum[t] : 0;
    lds[t] = v;
    __syncthreads();
    for (int d = 1; d < SCAN_B; d <<= 1) {
        int add = (t >= d) ? lds[t - d] : 0;
        __syncthreads();
        lds[t] += add;
        __syncthreads();
    }
    if (t < nb) bsum[t] = lds[t] - v;
}

__global__ void k_scan3(int* __restrict__ offs, const int* __restrict__ bsum, int NSs) {
    int g = blockIdx.x * SCAN_B + threadIdx.x;
    if (g < NSs) offs[g] += bsum[blockIdx.x];
}

// fallback-path scatter
__global__ void k_scatter(const int* __restrict__ src, const int* __restrict__ tgt,
                          const int* __restrict__ offs, int* __restrict__ cursor,
                          int2* __restrict__ csr, int E) {
    int e = blockIdx.x * blockDim.x + threadIdx.x;
    if (e >= E) return;
    int s = src[e];
    int pos = offs[s] + atomicAdd(&cursor[s], 1);
    csr[pos] = make_int2(tgt[e], e);
}

// ---------------- edge MLP: 2 edges per thread, fused pos atomic ----------------

__device__ __forceinline__ void edge_mlp(const float* __restrict__ x_t,
                                         const float* __restrict__ ea,
                                         const float* __restrict__ W1,
                                         const float* __restrict__ b1,
                                         const float* __restrict__ W2,
                                         const float* __restrict__ b2,
                                         int tt, int e, float* o) {
    float f[H1];
#pragma unroll
    for (int i = 0; i < FXT; i++) f[i] = x_t[(size_t)tt * FXT + i];
    const float2* e2 = (const float2*)(ea + (size_t)e * FE);
#pragma unroll
    for (int i = 0; i < FE / 2; i++) {
        float2 v = e2[i];
        f[FXT + 2 * i] = v.x;
        f[FXT + 2 * i + 1] = v.y;
    }
    float h[H1];
#pragma unroll
    for (int j = 0; j < H1; j++) {
        float acc = b1[j];
#pragma unroll
        for (int i = 0; i < H1; i++) acc = fmaf(f[i], W1[i * H1 + j], acc);
        h[j] = fmaxf(acc, 0.1f * acc);
    }
#pragma unroll
    for (int j = 0; j < H1; j++) {
        float acc = b2[j];
#pragma unroll
        for (int i = 0; i < H1; i++) acc = fmaf(h[i], W2[i * H1 + j], acc);
        o[j] = acc;
    }
}

__device__ __forceinline__ void pack_store(__half* __restrict__ buf, int pos,
                                           const float* o) {
    unsigned int w[8];
#pragma unroll
    for (int i = 0; i < 7; i++) {
        unsigned int lo = __half_as_ushort(__float2half(o[2 * i]));
        unsigned int hi = __half_as_ushort(__float2half(o[2 * i + 1]));
        w[i] = lo | (hi << 16);
    }
    w[7] = (unsigned int)__half_as_ushort(__float2half(o[14]));
    uint4* dst = (uint4*)(buf + (size_t)pos * 16);
    dst[0] = make_uint4(w[0], w[1], w[2], w[3]);
    dst[1] = make_uint4(w[4], w[5], w[6], w[7]);
}

__global__ __launch_bounds__(256) void k_edge2(
    const float* __restrict__ x_t, const float* __restrict__ ea,
    const float* __restrict__ W1, const float* __restrict__ b1,
    const float* __restrict__ W2, const float* __restrict__ b2,
    const int* __restrict__ src, const int* __restrict__ tgt,
    const int* __restrict__ offs, int* __restrict__ cursor,
    __half* __restrict__ buf, int E, int halfE)
{
    int gid = blockIdx.x * blockDim.x + threadIdx.x;
    if (gid >= halfE) return;
    int e0 = gid;
    int e1 = gid + halfE;
    bool v1 = (e1 < E);
    int e1c = v1 ? e1 : e0;

    int s0 = src[e0];
    int s1 = src[e1c];
    int t0 = tgt[e0];
    int t1 = tgt[e1c];

    // issue atomics early; results consumed only at the stores
    int pos0 = offs[s0] + atomicAdd(&cursor[s0], 1);
    int pos1 = 0;
    if (v1) pos1 = offs[s1] + atomicAdd(&cursor[s1], 1);

    float o0[H1], o1[H1];
    edge_mlp(x_t, ea, W1, b1, W2, b2, t0, e0, o0);
    edge_mlp(x_t, ea, W1, b1, W2, b2, t1, e1c, o1);

    pack_store(buf, pos0, o0);
    if (v1) pack_store(buf, pos1, o1);
}

// ---------------- moments + node MLP (8 lanes per node, half2) ----------------

__global__ __launch_bounds__(256) void k_moments(
    const float* __restrict__ x_s, const float* __restrict__ u,
    const float* __restrict__ W3, const float* __restrict__ b3,
    const float* __restrict__ W4, const float* __restrict__ b4,
    const int* __restrict__ batch_s,
    const int* __restrict__ cnt, const int* __restrict__ offs,
    const __half* __restrict__ buf,
    float* __restrict__ out, int NSs)
{
    __shared__ float sW3[H2 * FXS], sb3[FXS], sW4[FXS * FXS], sb4[FXS];
    __shared__ float feat[32][H2 + 3];   // 84-float stride
    __shared__ float l1s[32][12];

    for (int i = threadIdx.x; i < H2 * FXS; i += blockDim.x) sW3[i] = W3[i];
    for (int i = threadIdx.x; i < FXS * FXS; i += blockDim.x) sW4[i] = W4[i];
    if (threadIdx.x < FXS) { sb3[threadIdx.x] = b3[threadIdx.x]; sb4[threadIdx.x] = b4[threadIdx.x]; }
    __syncthreads();

    int g = threadIdx.x >> 3;        // node group within block (0..31)
    int j = threadIdx.x & 7;         // feature-pair lane
    int s = blockIdx.x * 32 + g;
    bool valid = (s < NSs);

    int n = 0, start = 0;
    if (valid) { n = cnt[s]; start = offs[s]; }

    if (valid) {
        // features fa=2j, fb=2j+1 (fb==15 is pad for j==7)
        float s1a = 0.f, s2a = 0.f, s3a = 0.f, s4a = 0.f;
        float s1b = 0.f, s2b = 0.f, s3b = 0.f, s4b = 0.f;
        const __half2* p = (const __half2*)(buf + (size_t)start * 16) + j;
#pragma unroll 4
        for (int k = 0; k < n; k++) {
            __half2 hv = p[(size_t)k * 8];
            float2 v = __half22float2(hv);
            float xa = v.x, xa2 = xa * xa;
            float xb = v.y, xb2 = xb * xb;
            s1a += xa;               s1b += xb;
            s2a = fmaf(xa, xa, s2a); s2b = fmaf(xb, xb, s2b);
            s3a = fmaf(xa2, xa, s3a); s3b = fmaf(xb2, xb, s3b);
            s4a = fmaf(xa2, xa2, s4a); s4b = fmaf(xb2, xb2, s4b);
        }
        float inv = 1.0f / (float)(n > 1 ? n : 1);
        {
            int fj = 2 * j;
            float a = s1a * inv, m2 = s2a * inv, m3 = s3a * inv, m4 = s4a * inv;
            float a2 = a * a;
            float var = m2 - a2;
            float bb = sqrtf(1e-6f + fmaxf(var, 0.0f));
            float c3 = m3 - 3.0f * a * m2 + 2.0f * a * a2;
            float c4 = m4 - 4.0f * a * m3 + 6.0f * a2 * m2 - 3.0f * a2 * a2;
            float ib = 1.0f / bb, ib2 = ib * ib;
            feat[g][FXS + 1 + fj] = a;
            feat[g][FXS + 1 + H1 + fj] = bb;
            feat[g][FXS + 1 + 2 * H1 + fj] = c3 * ib * ib2;
            feat[g][FXS + 1 + 3 * H1 + fj] = c4 * ib2 * ib2;
        }
        if (j < 7) {
            int fj = 2 * j + 1;
            float a = s1b * inv, m2 = s2b * inv, m3 = s3b * inv, m4 = s4b * inv;
            float a2 = a * a;
            float var = m2 - a2;
            float bb = sqrtf(1e-6f + fmaxf(var, 0.0f));
            float c3 = m3 - 3.0f * a * m2 + 2.0f * a * a2;
            float c4 = m4 - 4.0f * a * m3 + 6.0f * a2 * m2 - 3.0f * a2 * a2;
            float ib = 1.0f / bb, ib2 = ib * ib;
            feat[g][FXS + 1 + fj] = a;
            feat[g][FXS + 1 + H1 + fj] = bb;
            feat[g][FXS + 1 + 2 * H1 + fj] = c3 * ib * ib2;
            feat[g][FXS + 1 + 3 * H1 + fj] = c4 * ib2 * ib2;
        }
        int bidx = batch_s[s];
        for (int i = j; i < FXS; i += 8) {
            feat[g][i] = x_s[(size_t)s * FXS + i];
            feat[g][FXS + 1 + 4 * H1 + i] = u[(size_t)bidx * FU + i];
        }
        if (j == 0) feat[g][FXS] = (float)n;
    }
    __syncthreads();

    for (int idx = threadIdx.x; idx < 32 * FXS; idx += 256) {
        int gg = idx / FXS, jj = idx - gg * FXS;
        int ss = blockIdx.x * 32 + gg;
        if (ss < NSs) {
            float acc = sb3[jj];
#pragma unroll
            for (int i = 0; i < H2; i++) acc = fmaf(feat[gg][i], sW3[i * FXS + jj], acc);
            l1s[gg][jj] = fmaxf(acc, 0.1f * acc);
        }
    }
    __syncthreads();

    for (int idx = threadIdx.x; idx < 32 * FXS; idx += 256) {
        int gg = idx / FXS, jj = idx - gg * FXS;
        int ss = blockIdx.x * 32 + gg;
        if (ss < NSs) {
            float acc = sb4[jj];
#pragma unroll
            for (int i = 0; i < FXS; i++) acc = fmaf(l1s[gg][i], sW4[i * FXS + jj], acc);
            out[(size_t)ss * FXS + jj] = acc;
        }
    }
}

// ---------------- fallback: round-1 fused node kernel ----------------

__global__ __launch_bounds__(256) void k_node(
    const float* __restrict__ x_s, const float* __restrict__ x_t,
    const float* __restrict__ ea, const float* __restrict__ u,
    const float* __restrict__ W1, const float* __restrict__ b1,
    const float* __restrict__ W2, const float* __restrict__ b2,
    const float* __restrict__ W3, const float* __restrict__ b3,
    const float* __restrict__ W4, const float* __restrict__ b4,
    const int* __restrict__ batch_s,
    const int* __restrict__ cnt, const int* __restrict__ offs,
    const int2* __restrict__ csr,
    float* __restrict__ out, int NSs) {
    __shared__ float sW1[H1 * H1], sb1[H1], sW2[H1 * H1], sb2[H1];
    __shared__ float sW3[H2 * FXS], sb3[FXS], sW4[FXS * FXS], sb4[FXS];
    for (int i = threadIdx.x; i < H1 * H1; i += blockDim.x) { sW1[i] = W1[i]; sW2[i] = W2[i]; }
    for (int i = threadIdx.x; i < H2 * FXS; i += blockDim.x) sW3[i] = W3[i];
    for (int i = threadIdx.x; i < FXS * FXS; i += blockDim.x) sW4[i] = W4[i];
    if (threadIdx.x < H1) { sb1[threadIdx.x] = b1[threadIdx.x]; sb2[threadIdx.x] = b2[threadIdx.x]; }
    if (threadIdx.x < FXS) { sb3[threadIdx.x] = b3[threadIdx.x]; sb4[threadIdx.x] = b4[threadIdx.x]; }
    __syncthreads();

    int s = blockIdx.x * blockDim.x + threadIdx.x;
    if (s >= NSs) return;
    int n = cnt[s], start = offs[s];

    float s1[H1], s2[H1], s3[H1], s4[H1];
#pragma unroll
    for (int j = 0; j < H1; j++) { s1[j] = 0.f; s2[j] = 0.f; s3[j] = 0.f; s4[j] = 0.f; }

    for (int k = 0; k < n; k++) {
        int2 te = csr[start + k];
        int tt = te.x;
        const float* ear = ea + (size_t)te.y * FE;
        float f[H1];
#pragma unroll
        for (int i = 0; i < FXT; i++) f[i] = x_t[(size_t)tt * FXT + i];
        const float2* e2 = (const float2*)ear;
#pragma unroll
        for (int i = 0; i < FE / 2; i++) {
            float2 v = e2[i];
            f[FXT + 2 * i] = v.x;
            f[FXT + 2 * i + 1] = v.y;
        }
        float h[H1];
#pragma unroll
        for (int j = 0; j < H1; j++) {
            float acc = sb1[j];
#pragma unroll
            for (int i = 0; i < H1; i++) acc = fmaf(f[i], sW1[i * H1 + j], acc);
            h[j] = fmaxf(acc, 0.1f * acc);
        }
#pragma unroll
        for (int j = 0; j < H1; j++) {
            float acc = sb2[j];
#pragma unroll
            for (int i = 0; i < H1; i++) acc = fmaf(h[i], sW2[i * H1 + j], acc);
            float x = acc, x2 = x * x;
            s1[j] += x;
            s2[j] = fmaf(x, x, s2[j]);
            s3[j] = fmaf(x2, x, s3[j]);
            s4[j] = fmaf(x2, x2, s4[j]);
        }
    }

    float inv = 1.0f / (float)(n > 1 ? n : 1);
    float feat[H2];
#pragma unroll
    for (int i = 0; i < FXS; i++) feat[i] = x_s[(size_t)s * FXS + i];
    feat[FXS] = (float)n;
#pragma unroll
    for (int j = 0; j < H1; j++) {
        float a = s1[j] * inv, m2 = s2[j] * inv, m3 = s3[j] * inv, m4 = s4[j] * inv;
        float a2 = a * a;
        float var = m2 - a2;
        float bb = sqrtf(1e-6f + fmaxf(var, 0.0f));
        float c3 = m3 - 3.0f * a * m2 + 2.0f * a * a2;
        float c4 = m4 - 4.0f * a * m3 + 6.0f * a2 * m2 - 3.0f * a2 * a2;
        float ib = 1.0f / bb, ib2 = ib * ib;
        feat[FXS + 1 + j] = a;
        feat[FXS + 1 + H1 + j] = bb;
        feat[FXS + 1 + 2 * H1 + j] = c3 * ib * ib2;
        feat[FXS + 1 + 3 * H1 + j] = c4 * ib2 * ib2;
    }
    int bidx = batch_s[s];
#pragma unroll
    for (int i = 0; i < FU; i++) feat[FXS + 1 + 4 * H1 + i] = u[(size_t)bidx * FU + i];

    float l1[FXS];
#pragma unroll
    for (int j = 0; j < FXS; j++) {
        float acc = sb3[j];
#pragma unroll
        for (int i = 0; i < H2; i++) acc = fmaf(feat[i], sW3[i * FXS + j], acc);
        l1[j] = fmaxf(acc, 0.1f * acc);
    }
#pragma unroll
    for (int j = 0; j < FXS; j++) {
        float acc = sb4[j];
#pragma unroll
        for (int i = 0; i < FXS; i++) acc = fmaf(l1[i], sW4[i * FXS + j], acc);
        out[(size_t)s * FXS + j] = acc;
    }
}

extern "C" void kernel_launch(void* const* d_in, const int* in_sizes, int n_in,
                              void* d_out, int out_size, void* d_ws, size_t ws_size,
                              hipStream_t stream) {
    const float* x_s = (const float*)d_in[0];
    const float* x_t = (const float*)d_in[1];
    const float* ea  = (const float*)d_in[2];
    const float* u   = (const float*)d_in[3];
    const float* W1  = (const float*)d_in[4];
    const float* b1  = (const float*)d_in[5];
    const float* W2  = (const float*)d_in[6];
    const float* b2  = (const float*)d_in[7];
    const float* W3  = (const float*)d_in[8];
    const float* b3  = (const float*)d_in[9];
    const float* W4  = (const float*)d_in[10];
    const float* b4  = (const float*)d_in[11];
    const int* src   = (const int*)d_in[12];
    const int* tgt   = (const int*)d_in[13];
    const int* batch_s = (const int*)d_in[14];

    int NSs = in_sizes[0] / FXS;
    int E   = in_sizes[2] / FE;

    auto align_up = [](size_t x) { return (x + 255) & ~(size_t)255; };
    char* w = (char*)d_ws;
    int* cnt = (int*)w;     w += align_up((size_t)NSs * 4);
    int* offs = (int*)w;    w += align_up((size_t)NSs * 4);
    int* cursor = (int*)w;  w += align_up((size_t)NSs * 4);
    int* bsum = (int*)w;    w += 64 * 1024;
    char* tail = w;
    size_t head = (size_t)(tail - (char*)d_ws);
    size_t need_fast = head + (size_t)E * 32;

    hipMemsetAsync(cnt, 0, (size_t)NSs * 4, stream);
    hipMemsetAsync(cursor, 0, (size_t)NSs * 4, stream);

    k_hist<<<(E + 255) / 256, 256, 0, stream>>>(src, cnt, E);
    int nb = (NSs + SCAN_B - 1) / SCAN_B;
    k_scan1<<<nb, SCAN_B, 0, stream>>>(cnt, offs, bsum, NSs);
    k_scan2<<<1, SCAN_B, 0, stream>>>(bsum, nb);
    k_scan3<<<nb, SCAN_B, 0, stream>>>(offs, bsum, NSs);

    if (ws_size >= need_fast) {
        __half* buf = (__half*)tail;
        int halfE = (E + 1) / 2;
        k_edge2<<<(halfE + 255) / 256, 256, 0, stream>>>(
            x_t, ea, W1, b1, W2, b2, src, tgt, offs, cursor, buf, E, halfE);
        k_moments<<<(NSs + 31) / 32, 256, 0, stream>>>(
            x_s, u, W3, b3, W4, b4, batch_s, cnt, offs, buf, (float*)d_out, NSs);
    } else {
        int2* csr = (int2*)tail;
        k_scatter<<<(E + 255) / 256, 256, 0, stream>>>(src, tgt, offs, cursor, csr, E);
        k_node<<<(NSs + 255) / 256, 256, 0, stream>>>(
            x_s, x_t, ea, u, W1, b1, W2, b2, W3, b3, W4, b4,
            batch_s, cnt, offs, csr, (float*)d_out, NSs);
    }
}

// Round 4
// 375.207 us; speedup vs baseline: 3.8517x; 1.1177x over previous
//
#include <hip/hip_runtime.h>
#include <hip/hip_fp16.h>

#define H1 15
#define H2 81
#define FXS 10
#define FXT 5
#define FE 10
#define FU 10
#define SCAN_B 1024

typedef _Float16 half4 __attribute__((ext_vector_type(4)));
typedef _Float16 half8 __attribute__((ext_vector_type(8)));
typedef float floatx4 __attribute__((ext_vector_type(4)));

// ---------------- CSR build ----------------

__global__ void k_hist(const int* __restrict__ src, int* __restrict__ cnt, int E) {
    int e = blockIdx.x * blockDim.x + threadIdx.x;
    if (e < E) atomicAdd(&cnt[src[e]], 1);
}

__global__ void k_scan1(const int* __restrict__ cnt, int* __restrict__ offs,
                        int* __restrict__ bsum, int NSs) {
    __shared__ int lds[SCAN_B];
    int t = threadIdx.x, g = blockIdx.x * SCAN_B + t;
    int v = (g < NSs) ? cnt[g] : 0;
    lds[t] = v;
    __syncthreads();
    for (int d = 1; d < SCAN_B; d <<= 1) {
        int add = (t >= d) ? lds[t - d] : 0;
        __syncthreads();
        lds[t] += add;
        __syncthreads();
    }
    int incl = lds[t];
    if (g < NSs) offs[g] = incl - v;
    if (t == SCAN_B - 1) bsum[blockIdx.x] = incl;
}

__global__ void k_scan2(int* __restrict__ bsum, int nb) {
    __shared__ int lds[SCAN_B];
    int t = threadIdx.x;
    int v = (t < nb) ? bsum[t] : 0;
    lds[t] = v;
    __syncthreads();
    for (int d = 1; d < SCAN_B; d <<= 1) {
        int add = (t >= d) ? lds[t - d] : 0;
        __syncthreads();
        lds[t] += add;
        __syncthreads();
    }
    if (t < nb) bsum[t] = lds[t] - v;
}

__global__ void k_scan3(int* __restrict__ offs, const int* __restrict__ bsum, int NSs) {
    int g = blockIdx.x * SCAN_B + threadIdx.x;
    if (g < NSs) offs[g] += bsum[blockIdx.x];
}

// fallback-path scatter
__global__ void k_scatter(const int* __restrict__ src, const int* __restrict__ tgt,
                          const int* __restrict__ offs, int* __restrict__ cursor,
                          int2* __restrict__ csr, int E) {
    int e = blockIdx.x * blockDim.x + threadIdx.x;
    if (e >= E) return;
    int s = src[e];
    int pos = offs[s] + atomicAdd(&cursor[s], 1);
    csr[pos] = make_int2(tgt[e], e);
}

// ---------------- MFMA edge MLP ----------------
// GEMM1: H[mid][edge] = W1^T (A) x F^T (B) + b1 ; leaky
// GEMM2: O[out][edge] = W2^T (A) x H  (B) + b2
// D-fragment of GEMM1 == B-fragment of GEMM2 (row/k = 4*(l>>4)+i, col = l&15).
// Weights live in 4 regs/lane, loaded once. 64 edges per wave per pass.

__global__ __launch_bounds__(256) void k_edge_mfma(
    const float* __restrict__ x_t, const float* __restrict__ ea,
    const float* __restrict__ W1, const float* __restrict__ b1,
    const float* __restrict__ W2, const float* __restrict__ b2,
    const int* __restrict__ src, const int* __restrict__ tgt,
    const int* __restrict__ offs, int* __restrict__ cursor,
    __half* __restrict__ buf, int E)
{
    __shared__ _Float16 lds_f[4][64][16];
    __shared__ int lds_pos[4][64];

    int lane = threadIdx.x & 63;
    int w = threadIdx.x >> 6;
    int base = blockIdx.x * 256 + w * 64;   // this wave's 64-edge chunk
    int e = base + lane;
    bool valid = (e < E);
    int ec = valid ? e : (E - 1);

    // ---- weight / bias fragments (A-operand: lane holds A[m=lane&15][k=4*(lane>>4)+i]) ----
    int mo = lane & 15;
    int kb = (lane >> 4) * 4;
    half4 a1f, a2f;
    floatx4 c1f, c2f;
#pragma unroll
    for (int i = 0; i < 4; i++) {
        int kk = kb + i;
        bool wv = (kk < H1) && (mo < H1);
        a1f[i] = wv ? (_Float16)W1[kk * H1 + mo] : (_Float16)0.f;   // W1^T[mo][kk]
        a2f[i] = wv ? (_Float16)W2[kk * H1 + mo] : (_Float16)0.f;   // W2^T[mo][kk]
        c1f[i] = (kk < H1) ? b1[kk] : 0.f;   // D rows are 4*(l>>4)+i
        c2f[i] = (kk < H1) ? b2[kk] : 0.f;
    }

    // ---- phase A: gather features -> f16 -> LDS ; fused pos atomic ----
    int sidx = src[ec];
    int tti = tgt[ec];
    int pos = 0;
    if (valid) pos = offs[sidx] + atomicAdd(&cursor[sidx], 1);

    float f[H1];
    const float* xr = x_t + (size_t)tti * FXT;
#pragma unroll
    for (int i = 0; i < FXT; i++) f[i] = xr[i];
    const float2* er = (const float2*)(ea + (size_t)ec * FE);
#pragma unroll
    for (int i = 0; i < FE / 2; i++) {
        float2 v = er[i];
        f[FXT + 2 * i] = v.x;
        f[FXT + 2 * i + 1] = v.y;
    }

    half8 lo, hi;
#pragma unroll
    for (int i = 0; i < 8; i++) lo[i] = valid ? (_Float16)f[i] : (_Float16)0.f;
#pragma unroll
    for (int i = 8; i < 15; i++) hi[i - 8] = valid ? (_Float16)f[i] : (_Float16)0.f;
    hi[7] = (_Float16)0.f;   // pad feature 15

    *(half8*)&lds_f[w][lane][0] = lo;
    *(half8*)&lds_f[w][lane][8] = hi;
    lds_pos[w][lane] = pos;
    __syncthreads();

    // ---- phase B: 4 groups of 16 edges ----
    int c = lane >> 4;
    int em = lane & 15;
#pragma unroll
    for (int g = 0; g < 4; g++) {
        int eg = (g << 4) + em;
        half4 bf = *(const half4*)&lds_f[w][eg][c * 4];
        floatx4 d1 = __builtin_amdgcn_mfma_f32_16x16x16f16(a1f, bf, c1f, 0, 0, 0);
        half4 b2f;
#pragma unroll
        for (int i = 0; i < 4; i++) {
            float x = d1[i];
            x = fmaxf(x, 0.1f * x);
            b2f[i] = (_Float16)x;
        }
        floatx4 d2 = __builtin_amdgcn_mfma_f32_16x16x16f16(a2f, b2f, c2f, 0, 0, 0);
        if (base + eg < E) {
            int p = lds_pos[w][eg];
            union { _Float16 h[4]; uint2 u; } pk;
#pragma unroll
            for (int i = 0; i < 4; i++) pk.h[i] = (_Float16)d2[i];
            *(uint2*)((char*)buf + (size_t)p * 32 + c * 8) = pk.u;
        }
    }
}

// ---------------- moments + node MLP (8 lanes per node, half2) ----------------

__global__ __launch_bounds__(256) void k_moments(
    const float* __restrict__ x_s, const float* __restrict__ u,
    const float* __restrict__ W3, const float* __restrict__ b3,
    const float* __restrict__ W4, const float* __restrict__ b4,
    const int* __restrict__ batch_s,
    const int* __restrict__ cnt, const int* __restrict__ offs,
    const __half* __restrict__ buf,
    float* __restrict__ out, int NSs)
{
    __shared__ float sW3[H2 * FXS], sb3[FXS], sW4[FXS * FXS], sb4[FXS];
    __shared__ float feat[32][H2 + 3];
    __shared__ float l1s[32][12];

    for (int i = threadIdx.x; i < H2 * FXS; i += blockDim.x) sW3[i] = W3[i];
    for (int i = threadIdx.x; i < FXS * FXS; i += blockDim.x) sW4[i] = W4[i];
    if (threadIdx.x < FXS) { sb3[threadIdx.x] = b3[threadIdx.x]; sb4[threadIdx.x] = b4[threadIdx.x]; }
    __syncthreads();

    int g = threadIdx.x >> 3;
    int j = threadIdx.x & 7;
    int s = blockIdx.x * 32 + g;
    bool valid = (s < NSs);

    int n = 0, start = 0;
    if (valid) { n = cnt[s]; start = offs[s]; }

    if (valid) {
        float s1a = 0.f, s2a = 0.f, s3a = 0.f, s4a = 0.f;
        float s1b = 0.f, s2b = 0.f, s3b = 0.f, s4b = 0.f;
        const __half2* p = (const __half2*)(buf + (size_t)start * 16) + j;
#pragma unroll 4
        for (int k = 0; k < n; k++) {
            __half2 hv = p[(size_t)k * 8];
            float2 v = __half22float2(hv);
            float xa = v.x, xa2 = xa * xa;
            float xb = v.y, xb2 = xb * xb;
            s1a += xa;               s1b += xb;
            s2a = fmaf(xa, xa, s2a); s2b = fmaf(xb, xb, s2b);
            s3a = fmaf(xa2, xa, s3a); s3b = fmaf(xb2, xb, s3b);
            s4a = fmaf(xa2, xa2, s4a); s4b = fmaf(xb2, xb2, s4b);
        }
        float inv = 1.0f / (float)(n > 1 ? n : 1);
        {
            int fj = 2 * j;
            float a = s1a * inv, m2 = s2a * inv, m3 = s3a * inv, m4 = s4a * inv;
            float a2 = a * a;
            float var = m2 - a2;
            float bb = sqrtf(1e-6f + fmaxf(var, 0.0f));
            float c3 = m3 - 3.0f * a * m2 + 2.0f * a * a2;
            float c4 = m4 - 4.0f * a * m3 + 6.0f * a2 * m2 - 3.0f * a2 * a2;
            float ib = 1.0f / bb, ib2 = ib * ib;
            feat[g][FXS + 1 + fj] = a;
            feat[g][FXS + 1 + H1 + fj] = bb;
            feat[g][FXS + 1 + 2 * H1 + fj] = c3 * ib * ib2;
            feat[g][FXS + 1 + 3 * H1 + fj] = c4 * ib2 * ib2;
        }
        if (j < 7) {
            int fj = 2 * j + 1;
            float a = s1b * inv, m2 = s2b * inv, m3 = s3b * inv, m4 = s4b * inv;
            float a2 = a * a;
            float var = m2 - a2;
            float bb = sqrtf(1e-6f + fmaxf(var, 0.0f));
            float c3 = m3 - 3.0f * a * m2 + 2.0f * a * a2;
            float c4 = m4 - 4.0f * a * m3 + 6.0f * a2 * m2 - 3.0f * a2 * a2;
            float ib = 1.0f / bb, ib2 = ib * ib;
            feat[g][FXS + 1 + fj] = a;
            feat[g][FXS + 1 + H1 + fj] = bb;
            feat[g][FXS + 1 + 2 * H1 + fj] = c3 * ib * ib2;
            feat[g][FXS + 1 + 3 * H1 + fj] = c4 * ib2 * ib2;
        }
        int bidx = batch_s[s];
        for (int i = j; i < FXS; i += 8) {
            feat[g][i] = x_s[(size_t)s * FXS + i];
            feat[g][FXS + 1 + 4 * H1 + i] = u[(size_t)bidx * FU + i];
        }
        if (j == 0) feat[g][FXS] = (float)n;
    }
    __syncthreads();

    for (int idx = threadIdx.x; idx < 32 * FXS; idx += 256) {
        int gg = idx / FXS, jj = idx - gg * FXS;
        int ss = blockIdx.x * 32 + gg;
        if (ss < NSs) {
            float acc = sb3[jj];
#pragma unroll
            for (int i = 0; i < H2; i++) acc = fmaf(feat[gg][i], sW3[i * FXS + jj], acc);
            l1s[gg][jj] = fmaxf(acc, 0.1f * acc);
        }
    }
    __syncthreads();

    for (int idx = threadIdx.x; idx < 32 * FXS; idx += 256) {
        int gg = idx / FXS, jj = idx - gg * FXS;
        int ss = blockIdx.x * 32 + gg;
        if (ss < NSs) {
            float acc = sb4[jj];
#pragma unroll
            for (int i = 0; i < FXS; i++) acc = fmaf(l1s[gg][i], sW4[i * FXS + jj], acc);
            out[(size_t)ss * FXS + jj] = acc;
        }
    }
}

// ---------------- fallback: round-1 fused node kernel ----------------

__global__ __launch_bounds__(256) void k_node(
    const float* __restrict__ x_s, const float* __restrict__ x_t,
    const float* __restrict__ ea, const float* __restrict__ u,
    const float* __restrict__ W1, const float* __restrict__ b1,
    const float* __restrict__ W2, const float* __restrict__ b2,
    const float* __restrict__ W3, const float* __restrict__ b3,
    const float* __restrict__ W4, const float* __restrict__ b4,
    const int* __restrict__ batch_s,
    const int* __restrict__ cnt, const int* __restrict__ offs,
    const int2* __restrict__ csr,
    float* __restrict__ out, int NSs) {
    __shared__ float sW1[H1 * H1], sb1[H1], sW2[H1 * H1], sb2[H1];
    __shared__ float sW3[H2 * FXS], sb3[FXS], sW4[FXS * FXS], sb4[FXS];
    for (int i = threadIdx.x; i < H1 * H1; i += blockDim.x) { sW1[i] = W1[i]; sW2[i] = W2[i]; }
    for (int i = threadIdx.x; i < H2 * FXS; i += blockDim.x) sW3[i] = W3[i];
    for (int i = threadIdx.x; i < FXS * FXS; i += blockDim.x) sW4[i] = W4[i];
    if (threadIdx.x < H1) { sb1[threadIdx.x] = b1[threadIdx.x]; sb2[threadIdx.x] = b2[threadIdx.x]; }
    if (threadIdx.x < FXS) { sb3[threadIdx.x] = b3[threadIdx.x]; sb4[threadIdx.x] = b4[threadIdx.x]; }
    __syncthreads();

    int s = blockIdx.x * blockDim.x + threadIdx.x;
    if (s >= NSs) return;
    int n = cnt[s], start = offs[s];

    float s1[H1], s2[H1], s3[H1], s4[H1];
#pragma unroll
    for (int j = 0; j < H1; j++) { s1[j] = 0.f; s2[j] = 0.f; s3[j] = 0.f; s4[j] = 0.f; }

    for (int k = 0; k < n; k++) {
        int2 te = csr[start + k];
        int tt = te.x;
        const float* ear = ea + (size_t)te.y * FE;
        float f[H1];
#pragma unroll
        for (int i = 0; i < FXT; i++) f[i] = x_t[(size_t)tt * FXT + i];
        const float2* e2 = (const float2*)ear;
#pragma unroll
        for (int i = 0; i < FE / 2; i++) {
            float2 v = e2[i];
            f[FXT + 2 * i] = v.x;
            f[FXT + 2 * i + 1] = v.y;
        }
        float h[H1];
#pragma unroll
        for (int j = 0; j < H1; j++) {
            float acc = sb1[j];
#pragma unroll
            for (int i = 0; i < H1; i++) acc = fmaf(f[i], sW1[i * H1 + j], acc);
            h[j] = fmaxf(acc, 0.1f * acc);
        }
#pragma unroll
        for (int j = 0; j < H1; j++) {
            float acc = sb2[j];
#pragma unroll
            for (int i = 0; i < H1; i++) acc = fmaf(h[i], sW2[i * H1 + j], acc);
            float x = acc, x2 = x * x;
            s1[j] += x;
            s2[j] = fmaf(x, x, s2[j]);
            s3[j] = fmaf(x2, x, s3[j]);
            s4[j] = fmaf(x2, x2, s4[j]);
        }
    }

    float inv = 1.0f / (float)(n > 1 ? n : 1);
    float feat[H2];
#pragma unroll
    for (int i = 0; i < FXS; i++) feat[i] = x_s[(size_t)s * FXS + i];
    feat[FXS] = (float)n;
#pragma unroll
    for (int j = 0; j < H1; j++) {
        float a = s1[j] * inv, m2 = s2[j] * inv, m3 = s3[j] * inv, m4 = s4[j] * inv;
        float a2 = a * a;
        float var = m2 - a2;
        float bb = sqrtf(1e-6f + fmaxf(var, 0.0f));
        float c3 = m3 - 3.0f * a * m2 + 2.0f * a * a2;
        float c4 = m4 - 4.0f * a * m3 + 6.0f * a2 * m2 - 3.0f * a2 * a2;
        float ib = 1.0f / bb, ib2 = ib * ib;
        feat[FXS + 1 + j] = a;
        feat[FXS + 1 + H1 + j] = bb;
        feat[FXS + 1 + 2 * H1 + j] = c3 * ib * ib2;
        feat[FXS + 1 + 3 * H1 + j] = c4 * ib2 * ib2;
    }
    int bidx = batch_s[s];
#pragma unroll
    for (int i = 0; i < FU; i++) feat[FXS + 1 + 4 * H1 + i] = u[(size_t)bidx * FU + i];

    float l1[FXS];
#pragma unroll
    for (int j = 0; j < FXS; j++) {
        float acc = sb3[j];
#pragma unroll
        for (int i = 0; i < H2; i++) acc = fmaf(feat[i], sW3[i * FXS + j], acc);
        l1[j] = fmaxf(acc, 0.1f * acc);
    }
#pragma unroll
    for (int j = 0; j < FXS; j++) {
        float acc = sb4[j];
#pragma unroll
        for (int i = 0; i < FXS; i++) acc = fmaf(l1[i], sW4[i * FXS + j], acc);
        out[(size_t)s * FXS + j] = acc;
    }
}

extern "C" void kernel_launch(void* const* d_in, const int* in_sizes, int n_in,
                              void* d_out, int out_size, void* d_ws, size_t ws_size,
                              hipStream_t stream) {
    const float* x_s = (const float*)d_in[0];
    const float* x_t = (const float*)d_in[1];
    const float* ea  = (const float*)d_in[2];
    const float* u   = (const float*)d_in[3];
    const float* W1  = (const float*)d_in[4];
    const float* b1  = (const float*)d_in[5];
    const float* W2  = (const float*)d_in[6];
    const float* b2  = (const float*)d_in[7];
    const float* W3  = (const float*)d_in[8];
    const float* b3  = (const float*)d_in[9];
    const float* W4  = (const float*)d_in[10];
    const float* b4  = (const float*)d_in[11];
    const int* src   = (const int*)d_in[12];
    const int* tgt   = (const int*)d_in[13];
    const int* batch_s = (const int*)d_in[14];

    int NSs = in_sizes[0] / FXS;
    int E   = in_sizes[2] / FE;

    auto align_up = [](size_t x) { return (x + 255) & ~(size_t)255; };
    char* w = (char*)d_ws;
    int* cnt = (int*)w;     w += align_up((size_t)NSs * 4);
    int* offs = (int*)w;    w += align_up((size_t)NSs * 4);
    int* cursor = (int*)w;  w += align_up((size_t)NSs * 4);
    int* bsum = (int*)w;    w += 64 * 1024;
    char* tail = w;
    size_t head = (size_t)(tail - (char*)d_ws);
    size_t need_fast = head + (size_t)E * 32;

    hipMemsetAsync(cnt, 0, (size_t)NSs * 4, stream);
    hipMemsetAsync(cursor, 0, (size_t)NSs * 4, stream);

    k_hist<<<(E + 255) / 256, 256, 0, stream>>>(src, cnt, E);
    int nb = (NSs + SCAN_B - 1) / SCAN_B;
    k_scan1<<<nb, SCAN_B, 0, stream>>>(cnt, offs, bsum, NSs);
    k_scan2<<<1, SCAN_B, 0, stream>>>(bsum, nb);
    k_scan3<<<nb, SCAN_B, 0, stream>>>(offs, bsum, NSs);

    if (ws_size >= need_fast) {
        __half* buf = (__half*)tail;
        k_edge_mfma<<<(E + 255) / 256, 256, 0, stream>>>(
            x_t, ea, W1, b1, W2, b2, src, tgt, offs, cursor, buf, E);
        k_moments<<<(NSs + 31) / 32, 256, 0, stream>>>(
            x_s, u, W3, b3, W4, b4, batch_s, cnt, offs, buf, (float*)d_out, NSs);
    } else {
        int2* csr = (int2*)tail;
        k_scatter<<<(E + 255) / 256, 256, 0, stream>>>(src, tgt, offs, cursor, csr, E);
        k_node<<<(NSs + 255) / 256, 256, 0, stream>>>(
            x_s, x_t, ea, u, W1, b1, W2, b2, W3, b3, W4, b4,
            batch_s, cnt, offs, csr, (float*)d_out, NSs);
    }
}